// Round 1
// baseline (33.594 us; speedup 1.0000x reference)
//
#include <hip/hip_runtime.h>
#include <math.h>

// Problem constants (LearnedDRoPEEnergy): B=16, K=256, H=W=64, T=1.0
#define BB   16
#define KK   256
#define HH   64
#define WWID 64
#define HWSZ 4096        // H*W
#define NPOS 65536       // B*H*W
#define NWORDS 8         // K/32 packed words per position

// 16 fixed offsets: r in {1,2} axial+diagonal (4-neighbors are duplicates).
__device__ __constant__ int c_dy[16] = {-1, 1, 0, 0, -1, -1, 1, 1,  -2, 2, 0, 0, -2, -2, 2, 2};
__device__ __constant__ int c_dx[16] = { 0, 0,-1, 1, -1,  1,-1, 1,   0, 0,-2, 2, -2,  2,-2, 2};

// Kernel A: pack binary z (fp32 0/1) into bitplanes: pack[pos*8 + word].
// One thread per (word, pos). Consecutive threads -> consecutive pos -> fully
// coalesced reads of z for each k. Also zero-inits d_out (poisoned by harness).
__global__ __launch_bounds__(256) void pack_kernel(const float* __restrict__ z,
                                                   unsigned* __restrict__ pack,
                                                   float* __restrict__ out) {
    int t = blockIdx.x * 256 + threadIdx.x;      // 0 .. NPOS*NWORDS-1
    int word = t >> 16;                          // NPOS == 1<<16
    int pos  = t & (NPOS - 1);
    int b    = pos >> 12;                        // pos / HWSZ
    int hw   = pos & (HWSZ - 1);
    const float* base = z + (size_t)(b * KK + word * 32) * HWSZ + hw;
    unsigned acc = 0u;
#pragma unroll
    for (int j = 0; j < 32; ++j) {
        float v = base[(size_t)j * HWSZ];
        acc |= (v > 0.5f) ? (1u << j) : 0u;
    }
    pack[pos * NWORDS + word] = acc;
    if (t < BB) out[t] = 0.0f;
}

// Kernel B: per position, weighted Hamming distance to 16 toroidal neighbors
// via byte-LUT (32 tables x 256 entries in LDS), sigmoid gate, accumulate.
__global__ __launch_bounds__(256) void energy_kernel(const unsigned* __restrict__ pack,
                                                     const float* __restrict__ w_logit,
                                                     const float* __restrict__ tau_p,
                                                     float* __restrict__ out) {
    __shared__ float wtab[32 * 256];   // 32 KB: wtab[p][v] = sum of w[8p+j] over set bits j of v
    __shared__ float red[4];

    int tid = threadIdx.x;
    // --- build LUT: 8192 entries / 256 threads = 32 each (all same byte-pos p) ---
    {
        int p = tid >> 3;              // 0..31
        int vbase = (tid & 7) * 32;    // 8 threads cover v=0..255 for this p
        float wv[8];
#pragma unroll
        for (int j = 0; j < 8; ++j) {
            float x = w_logit[p * 8 + j];
            wv[j] = log1pf(expf(x));   // softplus, fp32 (x is tiny, no overflow)
        }
        for (int v = vbase; v < vbase + 32; ++v) {
            float s = 0.0f;
#pragma unroll
            for (int j = 0; j < 8; ++j) s += ((v >> j) & 1) ? wv[j] : 0.0f;
            wtab[p * 256 + v] = s;
        }
    }
    __syncthreads();

    float tau = tau_p[0];
    int pos = blockIdx.x * 256 + tid;            // one thread per position
    int b = pos >> 12;
    int h = (pos >> 6) & 63;
    int w = pos & 63;

    const uint4* pk = (const uint4*)pack;        // 32 B per position
    uint4 o0 = pk[pos * 2 + 0];
    uint4 o1 = pk[pos * 2 + 1];

    float e = 0.0f;
#pragma unroll
    for (int o = 0; o < 16; ++o) {
        int h2 = (h + c_dy[o]) & 63;             // roll(-dy): nbr = (h+dy) mod H
        int w2 = (w + c_dx[o]) & 63;
        int np = (b << 12) | (h2 << 6) | w2;
        uint4 n0 = pk[np * 2 + 0];
        uint4 n1 = pk[np * 2 + 1];
        unsigned x[8];
        x[0] = o0.x ^ n0.x; x[1] = o0.y ^ n0.y; x[2] = o0.z ^ n0.z; x[3] = o0.w ^ n0.w;
        x[4] = o1.x ^ n1.x; x[5] = o1.y ^ n1.y; x[6] = o1.z ^ n1.z; x[7] = o1.w ^ n1.w;
        float d = 0.0f;
#pragma unroll
        for (int i = 0; i < 8; ++i) {
            unsigned xi = x[i];
            d += wtab[(i * 4 + 0) * 256 + (xi & 255)];
            d += wtab[(i * 4 + 1) * 256 + ((xi >> 8) & 255)];
            d += wtab[(i * 4 + 2) * 256 + ((xi >> 16) & 255)];
            d += wtab[(i * 4 + 3) * 256 + (xi >> 24)];
        }
        // gate*d = d * sigmoid(tau - d) = d / (1 + exp(d - tau)); overflow -> 0, fine
        e += d / (1.0f + expf(d - tau));
    }

    // block reduction: all 256 threads in a block share the same b
#pragma unroll
    for (int s = 32; s > 0; s >>= 1) e += __shfl_down(e, s, 64);
    int lane = tid & 63, wv = tid >> 6;
    if (lane == 0) red[wv] = e;
    __syncthreads();
    if (tid == 0) {
        float s = red[0] + red[1] + red[2] + red[3];
        atomicAdd(out + b, s);
    }
}

extern "C" void kernel_launch(void* const* d_in, const int* in_sizes, int n_in,
                              void* d_out, int out_size, void* d_ws, size_t ws_size,
                              hipStream_t stream) {
    const float* z       = (const float*)d_in[0];   // (B,K,H,W) fp32, values 0/1
    const float* w_logit = (const float*)d_in[1];   // (K,) fp32
    const float* tau     = (const float*)d_in[2];   // scalar fp32
    float* out = (float*)d_out;                     // (B,) fp32
    unsigned* pack = (unsigned*)d_ws;               // needs NPOS*NWORDS*4 = 2 MB

    // Kernel A: 524288 threads = 2048 blocks of 256
    hipLaunchKernelGGL(pack_kernel, dim3(NPOS * NWORDS / 256), dim3(256), 0, stream,
                       z, pack, out);
    // Kernel B: 65536 threads = 256 blocks of 256
    hipLaunchKernelGGL(energy_kernel, dim3(NPOS / 256), dim3(256), 0, stream,
                       pack, w_logit, tau, out);
}